// Round 6
// baseline (386.607 us; speedup 1.0000x reference)
//
#include <hip/hip_runtime.h>

#define N 8192
#define CAP 64   // per-row column capacity; E[nnz]=16.4, P(>64) ~ 1e-18

typedef unsigned int u32;
typedef u32 u32x4 __attribute__((ext_vector_type(4)));

// K1 (fused): blocks 0..255 compute X = H @ W1 (8192x64 @ 64x64, f32);
// blocks 256..8447 stream one adj row each: count nnz -> deg=nnz+1 ->
// dinv=rsqrt(deg), and compact nonzero column indices.
// R5->R6 A/B: plain loads instead of __builtin_nontemporal_load (suspect NT
// bypass path throttles the 268 MB stream; everything else unchanged).
__global__ __launch_bounds__(256) void k_scan_xw1(const float* __restrict__ adj,
                                                  const float* __restrict__ H,
                                                  const float* __restrict__ W1,
                                                  float* __restrict__ X,
                                                  float* __restrict__ dinv,
                                                  int* __restrict__ rowcnt,
                                                  int* __restrict__ colidx) {
    __shared__ float w[64][64];                      // xw1 path: 16 KB
    __shared__ int cnt;                              // scan path
    const int t = threadIdx.x;

    if (blockIdx.x < 256) {                          // ---- xw1 path ----
        for (int i = t; i < 4096; i += 256) w[i >> 6][i & 63] = W1[i];
        __syncthreads();
        const int wave = t >> 6, lane = t & 63;
#pragma unroll
        for (int rr = 0; rr < 8; ++rr) {
            const int row = blockIdx.x * 32 + wave * 8 + rr;
            const float h = H[row * 64 + lane];
            float acc = 0.f;
#pragma unroll
            for (int k = 0; k < 64; ++k) {
                const float hk = __shfl(h, k, 64);
                acc += hk * w[k][lane];
            }
            X[row * 64 + lane] = acc;
        }
        return;
    }

    // ---- scan path ----
    const int row = blockIdx.x - 256;
    if (t == 0) cnt = 0;
    __syncthreads();
    const u32x4* r = (const u32x4*)(adj + (size_t)row * N);
    int* ci = colidx + (size_t)row * CAP;
#pragma unroll
    for (int it = 0; it < 8; ++it) {                 // 8192 floats / (256 thr * 4)
        const int i4 = it * 256 + t;
        const u32x4 v = r[i4];                       // plain global_load_dwordx4
        const int m = (v.x ? 1 : 0) | (v.y ? 2 : 0) | (v.z ? 4 : 0) | (v.w ? 8 : 0);
        if (m) {                                     // one exec-mask region per 16B
            const int e0 = i4 * 4;
            int s = atomicAdd(&cnt, __popc(m));
            if (m & 1) { if (s < CAP) ci[s] = e0;     ++s; }
            if (m & 2) { if (s < CAP) ci[s] = e0 + 1; ++s; }
            if (m & 4) { if (s < CAP) ci[s] = e0 + 2; ++s; }
            if (m & 8) { if (s < CAP) ci[s] = e0 + 3; ++s; }
        }
    }
    __syncthreads();
    if (t == 0) {
        const int c = cnt;
        rowcnt[row] = c < CAP ? c : CAP;
        dinv[row] = rsqrtf((float)c + 1.0f);         // deg = nnz + 1 (entries are 1.0)
    }
}

// K2: H1 = relu(d_i * (sum_{j in nz(i)} d_j X[j] + d_i X[i])), fused with
// Y = H1 @ W2 (64->16). One BLOCK per row: neighbors split across 4 waves,
// LDS cross-wave reduce, wave 0 does W2.
__global__ __launch_bounds__(256) void k_agg1(const float* __restrict__ X,
                                              const float* __restrict__ dinv,
                                              const int* __restrict__ rowcnt,
                                              const int* __restrict__ colidx,
                                              const float* __restrict__ W2,
                                              float* __restrict__ Y) {
    __shared__ float w2[64][16];                     // 4 KB
    __shared__ float part[3][64];
    const int t = threadIdx.x;
    for (int i = t; i < 1024; i += 256) w2[i >> 4][i & 15] = W2[i];   // issue before gather
    const int wave = t >> 6, lane = t & 63;
    const int row = blockIdx.x;
    const int cnt = rowcnt[row];
    const int* ci = colidx + (size_t)row * CAP;
    float acc = 0.f;
    for (int k = wave; k < cnt; k += 4) {
        const int j = ci[k];
        acc += dinv[j] * X[(size_t)j * 64 + lane];
    }
    const float di = dinv[row];
    if (wave == 0) acc += di * X[(size_t)row * 64 + lane];   // +I self term
    else part[wave - 1][lane] = acc;
    __syncthreads();
    if (wave == 0) {
        float h1 = di * (acc + part[0][lane] + part[1][lane] + part[2][lane]);
        h1 = fmaxf(h1, 0.f);                         // ReLU
        float y = 0.f;
#pragma unroll
        for (int k = 0; k < 64; ++k) y += __shfl(h1, k, 64) * w2[k][lane & 15];
        if (lane < 16) Y[row * 16 + lane] = y;
    }
}

// K3: H2 = d_i * (sum_{j} d_j Y[j] + d_i Y[i]) + row softmax (16 classes).
// One wave per row: lanes = 4 neighbor-groups x 16 features.
__global__ __launch_bounds__(256) void k_agg2(const float* __restrict__ Y,
                                              const float* __restrict__ dinv,
                                              const int* __restrict__ rowcnt,
                                              const int* __restrict__ colidx,
                                              float* __restrict__ out) {
    const int t = threadIdx.x;
    const int wave = t >> 6, lane = t & 63;
    const int row = blockIdx.x * 4 + wave;
    const int g = lane >> 4, c = lane & 15;
    const int cnt = rowcnt[row];
    const int* ci = colidx + (size_t)row * CAP;
    float acc = 0.f;
    for (int k = g; k < cnt; k += 4) {
        const int j = ci[k];
        acc += dinv[j] * Y[j * 16 + c];
    }
    const float di = dinv[row];
    if (g == 0) acc += di * Y[row * 16 + c];         // +I self term
    acc += __shfl_xor(acc, 32, 64);                  // fold 4 groups
    acc += __shfl_xor(acc, 16, 64);
    const float h2 = di * acc;
    float m = h2;
#pragma unroll
    for (int off = 1; off < 16; off <<= 1) m = fmaxf(m, __shfl_xor(m, off, 16));
    const float e = __expf(h2 - m);
    float s = e;
#pragma unroll
    for (int off = 1; off < 16; off <<= 1) s += __shfl_xor(s, off, 16);
    if (lane < 16) out[row * 16 + lane] = e / s;
}

extern "C" void kernel_launch(void* const* d_in, const int* in_sizes, int n_in,
                              void* d_out, int out_size, void* d_ws, size_t ws_size,
                              hipStream_t stream) {
    const float* H   = (const float*)d_in[0];   // [8192, 64]   f32
    const float* adj = (const float*)d_in[1];   // [8192, 8192] f32 (0/1)
    const float* W1  = (const float*)d_in[2];   // [64, 64]     f32
    const float* W2  = (const float*)d_in[3];   // [64, 16]     f32
    float* out = (float*)d_out;                 // [8192, 16]   f32

    char* w = (char*)d_ws;                      // total scratch ~4.6 MB
    float* dinv   = (float*)(w);                                            // 32 KB
    int*   rowcnt = (int*)(w + 32 * 1024);                                  // 32 KB
    int*   colidx = (int*)(w + 64 * 1024);                                  // 2 MB
    float* X      = (float*)(w + 64 * 1024 + (size_t)N * CAP * 4);          // 2 MB
    float* Y      = (float*)(w + 64 * 1024 + (size_t)N * CAP * 4
                               + (size_t)N * 64 * 4);                       // 512 KB

    k_scan_xw1<<<dim3(N + 256), dim3(256), 0, stream>>>(adj, H, W1, X, dinv, rowcnt, colidx);
    k_agg1    <<<dim3(N),       dim3(256), 0, stream>>>(X, dinv, rowcnt, colidx, W2, Y);
    k_agg2    <<<dim3(N / 4),   dim3(256), 0, stream>>>(Y, dinv, rowcnt, colidx, out);
}

// Round 7
// 366.396 us; speedup vs baseline: 1.0552x; 1.0552x over previous
//
#include <hip/hip_runtime.h>

#define N 8192
#define CAP 64   // per-row column capacity; E[nnz]=16.4, P(>64) ~ 1e-18

typedef unsigned int u32;
typedef u32 u32x4 __attribute__((ext_vector_type(4)));

// K1 (fused): blocks 0..255 compute X = H @ W1 (8192x64 @ 64x64, f32);
// blocks 256..8447 stream one adj row each: count nnz -> deg=nnz+1 ->
// dinv=rsqrt(deg), and compact nonzero column indices.
// R6 A/B showed NT loads are worth ~18 us (keep L2 clean for ws gathers) —
// restored. New: all 8 row-chunk loads hoisted into registers before any
// consumption, guaranteeing 8 outstanding loads/thread regardless of how the
// compiler schedules the branchy consumer.
__global__ __launch_bounds__(256) void k_scan_xw1(const float* __restrict__ adj,
                                                  const float* __restrict__ H,
                                                  const float* __restrict__ W1,
                                                  float* __restrict__ X,
                                                  float* __restrict__ dinv,
                                                  int* __restrict__ rowcnt,
                                                  int* __restrict__ colidx) {
    __shared__ float w[64][64];                      // xw1 path: 16 KB
    __shared__ int cnt;                              // scan path
    const int t = threadIdx.x;

    if (blockIdx.x < 256) {                          // ---- xw1 path ----
        for (int i = t; i < 4096; i += 256) w[i >> 6][i & 63] = W1[i];
        __syncthreads();
        const int wave = t >> 6, lane = t & 63;
#pragma unroll
        for (int rr = 0; rr < 8; ++rr) {
            const int row = blockIdx.x * 32 + wave * 8 + rr;
            const float h = H[row * 64 + lane];
            float acc = 0.f;
#pragma unroll
            for (int k = 0; k < 64; ++k) {
                const float hk = __shfl(h, k, 64);
                acc += hk * w[k][lane];
            }
            X[row * 64 + lane] = acc;
        }
        return;
    }

    // ---- scan path ----
    const int row = blockIdx.x - 256;
    if (t == 0) cnt = 0;
    __syncthreads();
    const u32x4* r = (const u32x4*)(adj + (size_t)row * N);
    int* ci = colidx + (size_t)row * CAP;

    u32x4 v[8];
#pragma unroll
    for (int it = 0; it < 8; ++it)                   // issue ALL loads first (MLP=8)
        v[it] = __builtin_nontemporal_load(&r[it * 256 + t]);

#pragma unroll
    for (int it = 0; it < 8; ++it) {
        const int i4 = it * 256 + t;
        const int m = (v[it].x ? 1 : 0) | (v[it].y ? 2 : 0) |
                      (v[it].z ? 4 : 0) | (v[it].w ? 8 : 0);
        if (m) {                                     // one exec-mask region per 16B
            const int e0 = i4 * 4;
            int s = atomicAdd(&cnt, __popc(m));
            if (m & 1) { if (s < CAP) ci[s] = e0;     ++s; }
            if (m & 2) { if (s < CAP) ci[s] = e0 + 1; ++s; }
            if (m & 4) { if (s < CAP) ci[s] = e0 + 2; ++s; }
            if (m & 8) { if (s < CAP) ci[s] = e0 + 3; ++s; }
        }
    }
    __syncthreads();
    if (t == 0) {
        const int c = cnt;
        rowcnt[row] = c < CAP ? c : CAP;
        dinv[row] = rsqrtf((float)c + 1.0f);         // deg = nnz + 1 (entries are 1.0)
    }
}

// K2: H1 = relu(d_i * (sum_{j in nz(i)} d_j X[j] + d_i X[i])), fused with
// Y = H1 @ W2 (64->16). One BLOCK per row: neighbors split across 4 waves,
// LDS cross-wave reduce, wave 0 does W2.
__global__ __launch_bounds__(256) void k_agg1(const float* __restrict__ X,
                                              const float* __restrict__ dinv,
                                              const int* __restrict__ rowcnt,
                                              const int* __restrict__ colidx,
                                              const float* __restrict__ W2,
                                              float* __restrict__ Y) {
    __shared__ float w2[64][16];                     // 4 KB
    __shared__ float part[3][64];
    const int t = threadIdx.x;
    for (int i = t; i < 1024; i += 256) w2[i >> 4][i & 15] = W2[i];   // issue before gather
    const int wave = t >> 6, lane = t & 63;
    const int row = blockIdx.x;
    const int cnt = rowcnt[row];
    const int* ci = colidx + (size_t)row * CAP;
    float acc = 0.f;
    for (int k = wave; k < cnt; k += 4) {
        const int j = ci[k];
        acc += dinv[j] * X[(size_t)j * 64 + lane];
    }
    const float di = dinv[row];
    if (wave == 0) acc += di * X[(size_t)row * 64 + lane];   // +I self term
    else part[wave - 1][lane] = acc;
    __syncthreads();
    if (wave == 0) {
        float h1 = di * (acc + part[0][lane] + part[1][lane] + part[2][lane]);
        h1 = fmaxf(h1, 0.f);                         // ReLU
        float y = 0.f;
#pragma unroll
        for (int k = 0; k < 64; ++k) y += __shfl(h1, k, 64) * w2[k][lane & 15];
        if (lane < 16) Y[row * 16 + lane] = y;
    }
}

// K3: H2 = d_i * (sum_{j} d_j Y[j] + d_i Y[i]) + row softmax (16 classes).
// One wave per row: lanes = 4 neighbor-groups x 16 features.
__global__ __launch_bounds__(256) void k_agg2(const float* __restrict__ Y,
                                              const float* __restrict__ dinv,
                                              const int* __restrict__ rowcnt,
                                              const int* __restrict__ colidx,
                                              float* __restrict__ out) {
    const int t = threadIdx.x;
    const int wave = t >> 6, lane = t & 63;
    const int row = blockIdx.x * 4 + wave;
    const int g = lane >> 4, c = lane & 15;
    const int cnt = rowcnt[row];
    const int* ci = colidx + (size_t)row * CAP;
    float acc = 0.f;
    for (int k = g; k < cnt; k += 4) {
        const int j = ci[k];
        acc += dinv[j] * Y[j * 16 + c];
    }
    const float di = dinv[row];
    if (g == 0) acc += di * Y[row * 16 + c];         // +I self term
    acc += __shfl_xor(acc, 32, 64);                  // fold 4 groups
    acc += __shfl_xor(acc, 16, 64);
    const float h2 = di * acc;
    float m = h2;
#pragma unroll
    for (int off = 1; off < 16; off <<= 1) m = fmaxf(m, __shfl_xor(m, off, 16));
    const float e = __expf(h2 - m);
    float s = e;
#pragma unroll
    for (int off = 1; off < 16; off <<= 1) s += __shfl_xor(s, off, 16);
    if (lane < 16) out[row * 16 + lane] = e / s;
}

extern "C" void kernel_launch(void* const* d_in, const int* in_sizes, int n_in,
                              void* d_out, int out_size, void* d_ws, size_t ws_size,
                              hipStream_t stream) {
    const float* H   = (const float*)d_in[0];   // [8192, 64]   f32
    const float* adj = (const float*)d_in[1];   // [8192, 8192] f32 (0/1)
    const float* W1  = (const float*)d_in[2];   // [64, 64]     f32
    const float* W2  = (const float*)d_in[3];   // [64, 16]     f32
    float* out = (float*)d_out;                 // [8192, 16]   f32

    char* w = (char*)d_ws;                      // total scratch ~4.6 MB
    float* dinv   = (float*)(w);                                            // 32 KB
    int*   rowcnt = (int*)(w + 32 * 1024);                                  // 32 KB
    int*   colidx = (int*)(w + 64 * 1024);                                  // 2 MB
    float* X      = (float*)(w + 64 * 1024 + (size_t)N * CAP * 4);          // 2 MB
    float* Y      = (float*)(w + 64 * 1024 + (size_t)N * CAP * 4
                               + (size_t)N * 64 * 4);                       // 512 KB

    k_scan_xw1<<<dim3(N + 256), dim3(256), 0, stream>>>(adj, H, W1, X, dinv, rowcnt, colidx);
    k_agg1    <<<dim3(N),       dim3(256), 0, stream>>>(X, dinv, rowcnt, colidx, W2, Y);
    k_agg2    <<<dim3(N / 4),   dim3(256), 0, stream>>>(Y, dinv, rowcnt, colidx, out);
}